// Round 27
// baseline (107.719 us; speedup 1.0000x reference)
//
#include <hip/hip_runtime.h>

typedef __attribute__((ext_vector_type(8))) short bf16x8;
typedef __attribute__((ext_vector_type(8))) unsigned short ushort8;
typedef __attribute__((ext_vector_type(4))) float f32x4;

#define IN_CH   32
#define OUT_CH  64
#define FEAT_CH 256
#define PTOT    32768
#define CTOT    90688
#define BEG1    0
#define BIAS1   8192
#define BEG2    8448
#define BIAS2   73984
#define BEG3    74240
#define BIAS3   90624
#define NFEATBLK 1417

__device__ __forceinline__ unsigned short f2bf(float f) {
  __bf16 h = (__bf16)f;
  return __builtin_bit_cast(unsigned short, h);
}
__device__ __forceinline__ float bf2f(unsigned short h) {
  union { unsigned u; float f; } v; v.u = ((unsigned)h) << 16;
  return v.f;
}
__device__ __forceinline__ unsigned pk_bf16(float lo, float hi) {  // D[15:0]=bf16(lo)
  unsigned r;
  asm("v_cvt_pk_bf16_f32 %0, %1, %2" : "=v"(r) : "v"(lo), "v"(hi));
  return r;
}
__device__ __forceinline__ void gload16(const void* g, void* l) {
  __builtin_amdgcn_global_load_lds(
      (const __attribute__((address_space(1))) unsigned int*)g,
      (__attribute__((address_space(3))) unsigned int*)l, 16, 0, 0);
}

// ============ mlp transpose: mlpT[n][k] = bf16(mlp[b][k][a]), n = b*64+a
__global__ __launch_bounds__(256) void mlp_tr(
    const float* __restrict__ mlp, unsigned short* __restrict__ mlpT) {
  __shared__ float t[64][65];
  const int b = blockIdx.x >> 2, k0 = (blockIdx.x & 3) << 6;
  const int tid = threadIdx.x;
  const int a = tid & 63, kq = tid >> 6;
#pragma unroll
  for (int j = 0; j < 16; ++j) {
    const int k = kq * 16 + j;
    t[k][a] = mlp[(size_t)b * 16384 + (size_t)(k0 + k) * 64 + a];
  }
  __syncthreads();
  const int a2 = tid >> 2, c4 = tid & 3;
  ushort8 o0, o1;
#pragma unroll
  for (int j = 0; j < 8; ++j)  o0[j] = f2bf(t[c4 * 16 + j][a2]);
#pragma unroll
  for (int j = 0; j < 8; ++j)  o1[j] = f2bf(t[c4 * 16 + 8 + j][a2]);
  unsigned short* dst = mlpT + (size_t)(b * 64 + a2) * 256 + k0 + c4 * 16;
  *(ushort8*)dst = o0;
  *(ushort8*)(dst + 8) = o1;
}

// ============ FUSED (R25 body; delta: alternating Bsh buffers, NO prefetch,
// ONE barrier per phase — trailing barrier removed, next phase writes the
// other buffer so early waves legally issue ahead).
__global__ __launch_bounds__(256) void fused_prep(
    const float* __restrict__ w_feat, const float* __restrict__ b_feat,
    const unsigned short* __restrict__ mlpT, unsigned short* __restrict__ featb,
    const float* __restrict__ coord_em, const float* __restrict__ coord_dt,
    const float* __restrict__ w_cd, const float* __restrict__ b_cd,
    unsigned short* __restrict__ xinb) {
  __shared__ unsigned short Bsh[2][32][256];  // 32KB alternating buffers
  const int tid = threadIdx.x;
  const int lane = tid & 63;

  if (blockIdx.x < NFEATBLK) {
    // ---------------- feat GEMM ----------------
    const int w = tid >> 6;
    const int l15 = lane & 15, l4 = lane >> 4;
    const int m0 = blockIdx.x * 64;           // 1417*64 == CTOT
    const int arow = m0 + w * 16 + l15;

    // A fragments: this lane's own row, full K, cvt once, live all phases.
    const float* __restrict__ ar = w_feat + (size_t)arow * 256 + l4 * 8;
    bf16x8 A[8];
#pragma unroll
    for (int ks = 0; ks < 8; ++ks) {
      const float4 p0 = *(const float4*)(ar + ks * 32);
      const float4 p1 = *(const float4*)(ar + ks * 32 + 4);
      unsigned t[4] = {pk_bf16(p0.x, p0.y), pk_bf16(p0.z, p0.w),
                       pk_bf16(p1.x, p1.y), pk_bf16(p1.z, p1.w)};
      A[ks] = __builtin_bit_cast(bf16x8, *(ulonglong2*)t);
    }

    const int c = m0 + w * 16 + l4 * 4;
    const float4 bia = *(const float4*)&b_feat[c];
    const int drow = lane >> 5;               // 0..1
    const int dchk = lane & 31;               // 0..31

    for (int np = 0; np < 8; ++np) {
      const int buf = np & 1;
      const int n0 = np * 32;
      // stage this phase's slice into its own buffer
#pragma unroll
      for (int j = 0; j < 4; ++j) {
        const int row = w * 8 + j * 2 + drow;
        gload16(mlpT + (size_t)(n0 + row) * 256 + ((dchk ^ (row & 7)) << 3),
                &Bsh[buf][w * 8 + j * 2][0]);
      }
      __syncthreads();   // vmcnt drain = staging complete

      f32x4 acc[2];
#pragma unroll
      for (int nf = 0; nf < 2; ++nf) acc[nf] = f32x4{0.f, 0.f, 0.f, 0.f};

#pragma unroll
      for (int ks = 0; ks < 8; ++ks) {
        bf16x8 Bv[2];
#pragma unroll
        for (int nf = 0; nf < 2; ++nf) {
          const int brow = nf * 16 + l15;
          const int cc = (ks * 4 + l4) ^ (brow & 7);
          Bv[nf] = *(const bf16x8*)&Bsh[buf][brow][cc * 8];
        }
#pragma unroll
        for (int nf = 0; nf < 2; ++nf)
          acc[nf] = __builtin_amdgcn_mfma_f32_16x16x32_bf16(A[ks], Bv[nf], acc[nf], 0, 0, 0);
      }

#pragma unroll
      for (int nf = 0; nf < 2; ++nf) {
        const int n = n0 + nf * 16 + l15;
        ushort4 o;
        o.x = f2bf(acc[nf][0] + bia.x);
        o.y = f2bf(acc[nf][1] + bia.y);
        o.z = f2bf(acc[nf][2] + bia.z);
        o.w = f2bf(acc[nf][3] + bia.w);
        *(ushort4*)(featb + (size_t)n * CTOT + c) = o;
      }
      // no trailing barrier: next phase writes the OTHER buffer; overwriting
      // this one requires passing the next barrier, which all readers reach
      // only after finishing this compute.
    }
  } else {
    // ---------------- coord_prep (verbatim body) ----------------
    const int ohalf = __builtin_amdgcn_readfirstlane((tid >> 6) & 1);
    const int pgrp = (blockIdx.x - NFEATBLK) * 2 + (tid >> 7);
    const int p_lin = pgrp * 64 + lane;
    const int b = p_lin >> 15, p = p_lin & 32767;

    const float* __restrict__ cdr = coord_dt + (size_t)p_lin * 64;
    float4 x[16];
#pragma unroll
    for (int j = 0; j < 16; ++j) x[j] = *(const float4*)(cdr + j * 4);
    __builtin_amdgcn_sched_barrier(0);

    float acc[16];
#pragma unroll
    for (int oo = 0; oo < 16; ++oo) acc[oo] = 0.f;
    const float* __restrict__ wr = w_cd + (size_t)(ohalf * 16) * 64;
#pragma unroll
    for (int oo = 0; oo < 16; ++oo) {
#pragma unroll
      for (int j = 0; j < 16; ++j) {
        acc[oo] = fmaf(wr[oo * 64 + j * 4 + 0], x[j].x, acc[oo]);
        acc[oo] = fmaf(wr[oo * 64 + j * 4 + 1], x[j].y, acc[oo]);
        acc[oo] = fmaf(wr[oo * 64 + j * 4 + 2], x[j].z, acc[oo]);
        acc[oo] = fmaf(wr[oo * 64 + j * 4 + 3], x[j].w, acc[oo]);
      }
    }

    float e[16];
#pragma unroll
    for (int oo = 0; oo < 16; ++oo) {
      const int o = ohalf * 16 + oo;
      e[oo] = acc[oo] + b_cd[o] + coord_em[((size_t)(b * IN_CH + o)) * PTOT + p];
    }
    const int s = p >> 12, rem = p & 4095;
    const int oh = rem >> 6, ow = rem & 63;
    const int a = ((oh >> 3) << 3) | (ow >> 3);
    const int pp = (s << 6) | ((oh & 7) << 3) | (ow & 7);
    unsigned short* __restrict__ dst =
        xinb + ((size_t)((b << 6) + a) * 512 + pp) * IN_CH + ohalf * 16;
    unsigned u[8];
#pragma unroll
    for (int q = 0; q < 8; ++q) u[q] = pk_bf16(e[2 * q], e[2 * q + 1]);
    *(ulonglong2*)dst = *(ulonglong2*)&u[0];
    *(ulonglong2*)(dst + 8) = *(ulonglong2*)&u[4];
  }
}

// ============ Stage C: swapped-operand MFMA MLP (R20-passing body, unchanged).
__global__ __launch_bounds__(512, 4) void tile_mlp(
    const unsigned short* __restrict__ featb, const unsigned short* __restrict__ xinb,
    float* __restrict__ out) {
  __shared__ unsigned short h[128][264];   // 67.6KB, row stride 528B (2-way banks: free)
  const int blk = blockIdx.x;
  const int tile = (blk & 7) * 32 + (blk >> 4);   // both halves of a tile -> same XCD
  const int half = (blk >> 3) & 1;
  const int tid = threadIdx.x;
  const int lane = tid & 63;
  const int wv = tid >> 6;
  const int wr = wv & 3, wc = wv >> 2;
  const int l15 = lane & 15, l4 = lane >> 4;
  const unsigned short* __restrict__ F = featb + (size_t)tile * CTOT;
  const int bb = tile >> 6, aa = tile & 63;
  const int ah = aa >> 3, aw = aa & 7;

  for (int ch2 = 0; ch2 < 2; ++ch2) {
    const int p0 = half * 256 + ch2 * 128;
    // ---- layer 1: [256 ch] x [128 px], K=32
    f32x4 a1[4][4];
#pragma unroll
    for (int mf = 0; mf < 4; ++mf) {
      const ushort4 bq = *(const ushort4*)(F + BIAS1 + wr * 64 + mf * 16 + l4 * 4);
      const f32x4 bi = {bf2f(bq.x), bf2f(bq.y), bf2f(bq.z), bf2f(bq.w)};
#pragma unroll
      for (int nf = 0; nf < 4; ++nf) a1[mf][nf] = bi;
    }
    {
      bf16x8 W1[4];
#pragma unroll
      for (int mf = 0; mf < 4; ++mf)
        W1[mf] = *(const bf16x8*)(F + BEG1 + (size_t)(wr * 64 + mf * 16 + l15) * 32 + l4 * 8);
#pragma unroll
      for (int nf = 0; nf < 4; ++nf) {
        const bf16x8 X1 = *(const bf16x8*)(xinb +
            ((size_t)tile * 512 + p0 + wc * 64 + nf * 16 + l15) * IN_CH + l4 * 8);
#pragma unroll
        for (int mf = 0; mf < 4; ++mf)
          a1[mf][nf] = __builtin_amdgcn_mfma_f32_16x16x32_bf16(W1[mf], X1, a1[mf][nf], 0, 0, 0);
      }
    }
#pragma unroll
    for (int mf = 0; mf < 4; ++mf)
#pragma unroll
      for (int nf = 0; nf < 4; ++nf) {
        float v0 = a1[mf][nf][0]; v0 = fmaxf(v0, 0.01f * v0);
        float v1 = a1[mf][nf][1]; v1 = fmaxf(v1, 0.01f * v1);
        float v2 = a1[mf][nf][2]; v2 = fmaxf(v2, 0.01f * v2);
        float v3 = a1[mf][nf][3]; v3 = fmaxf(v3, 0.01f * v3);
        uint2 pk; pk.x = pk_bf16(v0, v1); pk.y = pk_bf16(v2, v3);
        *(uint2*)&h[wc * 64 + nf * 16 + l15][wr * 64 + mf * 16 + l4 * 4] = pk;
      }
    __syncthreads();
    // ---- layer 2: [256 ch] x [128 px], K=256
    f32x4 a2[4][4];
#pragma unroll
    for (int mf = 0; mf < 4; ++mf) {
      const ushort4 bq = *(const ushort4*)(F + BIAS2 + wr * 64 + mf * 16 + l4 * 4);
      const f32x4 bi = {bf2f(bq.x), bf2f(bq.y), bf2f(bq.z), bf2f(bq.w)};
#pragma unroll
      for (int nf = 0; nf < 4; ++nf) a2[mf][nf] = bi;
    }
#pragma unroll 2
    for (int ks = 0; ks < 8; ++ks) {
      bf16x8 W2[4];
#pragma unroll
      for (int mf = 0; mf < 4; ++mf)
        W2[mf] = *(const bf16x8*)(F + BEG2 + (size_t)(wr * 64 + mf * 16 + l15) * 256 + ks * 32 + l4 * 8);
#pragma unroll
      for (int nf = 0; nf < 4; ++nf) {
        const bf16x8 X2 = *(const bf16x8*)&h[wc * 64 + nf * 16 + l15][ks * 32 + l4 * 8];
#pragma unroll
        for (int mf = 0; mf < 4; ++mf)
          a2[mf][nf] = __builtin_amdgcn_mfma_f32_16x16x32_bf16(W2[mf], X2, a2[mf][nf], 0, 0, 0);
      }
    }
    __syncthreads();
#pragma unroll
    for (int mf = 0; mf < 4; ++mf)
#pragma unroll
      for (int nf = 0; nf < 4; ++nf) {
        float v0 = a2[mf][nf][0]; v0 = fmaxf(v0, 0.01f * v0);
        float v1 = a2[mf][nf][1]; v1 = fmaxf(v1, 0.01f * v1);
        float v2 = a2[mf][nf][2]; v2 = fmaxf(v2, 0.01f * v2);
        float v3 = a2[mf][nf][3]; v3 = fmaxf(v3, 0.01f * v3);
        uint2 pk; pk.x = pk_bf16(v0, v1); pk.y = pk_bf16(v2, v3);
        *(uint2*)&h[wc * 64 + nf * 16 + l15][wr * 64 + mf * 16 + l4 * 4] = pk;
      }
    __syncthreads();
    // ---- layer 3: [64 ch] x [128 px], K=256 -> direct out stores
    f32x4 a3[4];
    {
      const ushort4 bq = *(const ushort4*)(F + BIAS3 + wr * 16 + l4 * 4);
      const f32x4 bi = {bf2f(bq.x), bf2f(bq.y), bf2f(bq.z), bf2f(bq.w)};
#pragma unroll
      for (int nf = 0; nf < 4; ++nf) a3[nf] = bi;
    }
#pragma unroll 2
    for (int ks = 0; ks < 8; ++ks) {
      const bf16x8 W3 = *(const bf16x8*)(F + BEG3 + (size_t)(wr * 16 + l15) * 256 + ks * 32 + l4 * 8);
#pragma unroll
      for (int nf = 0; nf < 4; ++nf) {
        const bf16x8 X3 = *(const bf16x8*)&h[wc * 64 + nf * 16 + l15][ks * 32 + l4 * 8];
        a3[nf] = __builtin_amdgcn_mfma_f32_16x16x32_bf16(W3, X3, a3[nf], 0, 0, 0);
      }
    }
#pragma unroll
    for (int nf = 0; nf < 4; ++nf) {
      const int p = p0 + wc * 64 + nf * 16 + l15;
      const int s = p >> 6, ph = (p >> 3) & 7, pw = p & 7;
      const size_t rowcol = (size_t)s * 4096 + (ah * 8 + ph) * 64 + aw * 8 + pw;
#pragma unroll
      for (int oc = 0; oc < 4; ++oc) {
        const int o = wr * 16 + l4 * 4 + oc;
        out[(size_t)(bb * 64 + o) * 32768 + rowcol] = a3[nf][oc];
      }
    }
    __syncthreads();
  }
}

extern "C" void kernel_launch(void* const* d_in, const int* in_sizes, int n_in,
                              void* d_out, int out_size, void* d_ws, size_t ws_size,
                              hipStream_t stream) {
  const float* mlp      = (const float*)d_in[0];
  const float* coord_em = (const float*)d_in[1];
  const float* coord_dt = (const float*)d_in[2];
  const float* w_cd     = (const float*)d_in[3];
  const float* b_cd     = (const float*)d_in[4];
  const float* w_feat   = (const float*)d_in[5];
  const float* b_feat   = (const float*)d_in[6];
  float* out = (float*)d_out;
  unsigned short* featb = (unsigned short*)d_ws;                         // 46,432,256
  unsigned short* xinb  = (unsigned short*)((char*)d_ws + 46432256ull);  // 8,388,608
  unsigned short* mlpT  = (unsigned short*)((char*)d_ws + 54820864ull);  // 131,072

  mlp_tr<<<16, 256, 0, stream>>>(mlp, mlpT);
  fused_prep<<<NFEATBLK + 1024, 256, 0, stream>>>(
      w_feat, b_feat, mlpT, featb, coord_em, coord_dt, w_cd, b_cd, xinb);
  tile_mlp<<<512, 512, 0, stream>>>(featb, xinb, out);
}

// Round 28
// 102.987 us; speedup vs baseline: 1.0460x; 1.0460x over previous
//
#include <hip/hip_runtime.h>

typedef __attribute__((ext_vector_type(8))) short bf16x8;
typedef __attribute__((ext_vector_type(8))) unsigned short ushort8;
typedef __attribute__((ext_vector_type(4))) float f32x4;

#define IN_CH   32
#define OUT_CH  64
#define FEAT_CH 256
#define PTOT    32768
#define CTOT    90688
#define BEG1    0
#define BIAS1   8192
#define BEG2    8448
#define BIAS2   73984
#define BEG3    74240
#define BIAS3   90624
#define NFEATBLK 1417

__device__ __forceinline__ unsigned short f2bf(float f) {
  __bf16 h = (__bf16)f;
  return __builtin_bit_cast(unsigned short, h);
}
__device__ __forceinline__ float bf2f(unsigned short h) {
  union { unsigned u; float f; } v; v.u = ((unsigned)h) << 16;
  return v.f;
}
__device__ __forceinline__ unsigned pk_bf16(float lo, float hi) {  // D[15:0]=bf16(lo)
  unsigned r;
  asm("v_cvt_pk_bf16_f32 %0, %1, %2" : "=v"(r) : "v"(lo), "v"(hi));
  return r;
}
__device__ __forceinline__ void gload16(const void* g, void* l) {
  __builtin_amdgcn_global_load_lds(
      (const __attribute__((address_space(1))) unsigned int*)g,
      (__attribute__((address_space(3))) unsigned int*)l, 16, 0, 0);
}

// ============ mlp transpose: mlpT[n][k] = bf16(mlp[b][k][a]), n = b*64+a
__global__ __launch_bounds__(256) void mlp_tr(
    const float* __restrict__ mlp, unsigned short* __restrict__ mlpT) {
  __shared__ float t[64][65];
  const int b = blockIdx.x >> 2, k0 = (blockIdx.x & 3) << 6;
  const int tid = threadIdx.x;
  const int a = tid & 63, kq = tid >> 6;
#pragma unroll
  for (int j = 0; j < 16; ++j) {
    const int k = kq * 16 + j;
    t[k][a] = mlp[(size_t)b * 16384 + (size_t)(k0 + k) * 64 + a];
  }
  __syncthreads();
  const int a2 = tid >> 2, c4 = tid & 3;
  ushort8 o0, o1;
#pragma unroll
  for (int j = 0; j < 8; ++j)  o0[j] = f2bf(t[c4 * 16 + j][a2]);
#pragma unroll
  for (int j = 0; j < 8; ++j)  o1[j] = f2bf(t[c4 * 16 + 8 + j][a2]);
  unsigned short* dst = mlpT + (size_t)(b * 64 + a2) * 256 + k0 + c4 * 16;
  *(ushort8*)dst = o0;
  *(ushort8*)(dst + 8) = o1;
}

// ============ FUSED (R25-passing build): blocks 0..1416 feat, 1417..2440 coord.
// Feat: A in registers (lane's own row, 32 VGPR), Bsh single 16KB buffer
// staged via source-swizzled global_load_lds, 8 np phases.
__global__ __launch_bounds__(256) void fused_prep(
    const float* __restrict__ w_feat, const float* __restrict__ b_feat,
    const unsigned short* __restrict__ mlpT, unsigned short* __restrict__ featb,
    const float* __restrict__ coord_em, const float* __restrict__ coord_dt,
    const float* __restrict__ w_cd, const float* __restrict__ b_cd,
    unsigned short* __restrict__ xinb) {
  __shared__ unsigned short Bsh[32][256];     // 16KB (swizzled, no pad)
  const int tid = threadIdx.x;
  const int lane = tid & 63;

  if (blockIdx.x < NFEATBLK) {
    // ---------------- feat GEMM ----------------
    const int w = tid >> 6;
    const int l15 = lane & 15, l4 = lane >> 4;
    const int m0 = blockIdx.x * 64;           // 1417*64 == CTOT
    const int arow = m0 + w * 16 + l15;

    // A fragments: this lane's own row, full K, cvt once, live all phases.
    const float* __restrict__ ar = w_feat + (size_t)arow * 256 + l4 * 8;
    bf16x8 A[8];
#pragma unroll
    for (int ks = 0; ks < 8; ++ks) {
      const float4 p0 = *(const float4*)(ar + ks * 32);
      const float4 p1 = *(const float4*)(ar + ks * 32 + 4);
      unsigned t[4] = {pk_bf16(p0.x, p0.y), pk_bf16(p0.z, p0.w),
                       pk_bf16(p1.x, p1.y), pk_bf16(p1.z, p1.w)};
      A[ks] = __builtin_bit_cast(bf16x8, *(ulonglong2*)t);
    }

    const int c = m0 + w * 16 + l4 * 4;
    const float4 bia = *(const float4*)&b_feat[c];
    const int drow = lane >> 5;               // 0..1
    const int dchk = lane & 31;               // 0..31

    for (int np = 0; np < 8; ++np) {
      const int n0 = np * 32;
#pragma unroll
      for (int j = 0; j < 4; ++j) {
        const int row = w * 8 + j * 2 + drow;
        gload16(mlpT + (size_t)(n0 + row) * 256 + ((dchk ^ (row & 7)) << 3),
                &Bsh[w * 8 + j * 2][0]);
      }
      __syncthreads();   // vmcnt drain = staging complete

      f32x4 acc[2];
#pragma unroll
      for (int nf = 0; nf < 2; ++nf) acc[nf] = f32x4{0.f, 0.f, 0.f, 0.f};

#pragma unroll
      for (int ks = 0; ks < 8; ++ks) {
        bf16x8 Bv[2];
#pragma unroll
        for (int nf = 0; nf < 2; ++nf) {
          const int brow = nf * 16 + l15;
          const int cc = (ks * 4 + l4) ^ (brow & 7);
          Bv[nf] = *(const bf16x8*)&Bsh[brow][cc * 8];
        }
#pragma unroll
        for (int nf = 0; nf < 2; ++nf)
          acc[nf] = __builtin_amdgcn_mfma_f32_16x16x32_bf16(A[ks], Bv[nf], acc[nf], 0, 0, 0);
      }

#pragma unroll
      for (int nf = 0; nf < 2; ++nf) {
        const int n = n0 + nf * 16 + l15;
        ushort4 o;
        o.x = f2bf(acc[nf][0] + bia.x);
        o.y = f2bf(acc[nf][1] + bia.y);
        o.z = f2bf(acc[nf][2] + bia.z);
        o.w = f2bf(acc[nf][3] + bia.w);
        *(ushort4*)(featb + (size_t)n * CTOT + c) = o;
      }
      __syncthreads();   // Bsh reads done before next pass overwrites
    }
  } else {
    // ---------------- coord_prep (verbatim body) ----------------
    const int ohalf = __builtin_amdgcn_readfirstlane((tid >> 6) & 1);
    const int pgrp = (blockIdx.x - NFEATBLK) * 2 + (tid >> 7);
    const int p_lin = pgrp * 64 + lane;
    const int b = p_lin >> 15, p = p_lin & 32767;

    const float* __restrict__ cdr = coord_dt + (size_t)p_lin * 64;
    float4 x[16];
#pragma unroll
    for (int j = 0; j < 16; ++j) x[j] = *(const float4*)(cdr + j * 4);
    __builtin_amdgcn_sched_barrier(0);

    float acc[16];
#pragma unroll
    for (int oo = 0; oo < 16; ++oo) acc[oo] = 0.f;
    const float* __restrict__ wr = w_cd + (size_t)(ohalf * 16) * 64;
#pragma unroll
    for (int oo = 0; oo < 16; ++oo) {
#pragma unroll
      for (int j = 0; j < 16; ++j) {
        acc[oo] = fmaf(wr[oo * 64 + j * 4 + 0], x[j].x, acc[oo]);
        acc[oo] = fmaf(wr[oo * 64 + j * 4 + 1], x[j].y, acc[oo]);
        acc[oo] = fmaf(wr[oo * 64 + j * 4 + 2], x[j].z, acc[oo]);
        acc[oo] = fmaf(wr[oo * 64 + j * 4 + 3], x[j].w, acc[oo]);
      }
    }

    float e[16];
#pragma unroll
    for (int oo = 0; oo < 16; ++oo) {
      const int o = ohalf * 16 + oo;
      e[oo] = acc[oo] + b_cd[o] + coord_em[((size_t)(b * IN_CH + o)) * PTOT + p];
    }
    const int s = p >> 12, rem = p & 4095;
    const int oh = rem >> 6, ow = rem & 63;
    const int a = ((oh >> 3) << 3) | (ow >> 3);
    const int pp = (s << 6) | ((oh & 7) << 3) | (ow & 7);
    unsigned short* __restrict__ dst =
        xinb + ((size_t)((b << 6) + a) * 512 + pp) * IN_CH + ohalf * 16;
    unsigned u[8];
#pragma unroll
    for (int q = 0; q < 8; ++q) u[q] = pk_bf16(e[2 * q], e[2 * q + 1]);
    *(ulonglong2*)dst = *(ulonglong2*)&u[0];
    *(ulonglong2*)(dst + 8) = *(ulonglong2*)&u[4];
  }
}

// ============ Stage C: swapped-operand MFMA MLP (R20-passing body, unchanged).
__global__ __launch_bounds__(512, 4) void tile_mlp(
    const unsigned short* __restrict__ featb, const unsigned short* __restrict__ xinb,
    float* __restrict__ out) {
  __shared__ unsigned short h[128][264];   // 67.6KB, row stride 528B (2-way banks: free)
  const int blk = blockIdx.x;
  const int tile = (blk & 7) * 32 + (blk >> 4);   // both halves of a tile -> same XCD
  const int half = (blk >> 3) & 1;
  const int tid = threadIdx.x;
  const int lane = tid & 63;
  const int wv = tid >> 6;
  const int wr = wv & 3, wc = wv >> 2;
  const int l15 = lane & 15, l4 = lane >> 4;
  const unsigned short* __restrict__ F = featb + (size_t)tile * CTOT;
  const int bb = tile >> 6, aa = tile & 63;
  const int ah = aa >> 3, aw = aa & 7;

  for (int ch2 = 0; ch2 < 2; ++ch2) {
    const int p0 = half * 256 + ch2 * 128;
    // ---- layer 1: [256 ch] x [128 px], K=32
    f32x4 a1[4][4];
#pragma unroll
    for (int mf = 0; mf < 4; ++mf) {
      const ushort4 bq = *(const ushort4*)(F + BIAS1 + wr * 64 + mf * 16 + l4 * 4);
      const f32x4 bi = {bf2f(bq.x), bf2f(bq.y), bf2f(bq.z), bf2f(bq.w)};
#pragma unroll
      for (int nf = 0; nf < 4; ++nf) a1[mf][nf] = bi;
    }
    {
      bf16x8 W1[4];
#pragma unroll
      for (int mf = 0; mf < 4; ++mf)
        W1[mf] = *(const bf16x8*)(F + BEG1 + (size_t)(wr * 64 + mf * 16 + l15) * 32 + l4 * 8);
#pragma unroll
      for (int nf = 0; nf < 4; ++nf) {
        const bf16x8 X1 = *(const bf16x8*)(xinb +
            ((size_t)tile * 512 + p0 + wc * 64 + nf * 16 + l15) * IN_CH + l4 * 8);
#pragma unroll
        for (int mf = 0; mf < 4; ++mf)
          a1[mf][nf] = __builtin_amdgcn_mfma_f32_16x16x32_bf16(W1[mf], X1, a1[mf][nf], 0, 0, 0);
      }
    }
#pragma unroll
    for (int mf = 0; mf < 4; ++mf)
#pragma unroll
      for (int nf = 0; nf < 4; ++nf) {
        float v0 = a1[mf][nf][0]; v0 = fmaxf(v0, 0.01f * v0);
        float v1 = a1[mf][nf][1]; v1 = fmaxf(v1, 0.01f * v1);
        float v2 = a1[mf][nf][2]; v2 = fmaxf(v2, 0.01f * v2);
        float v3 = a1[mf][nf][3]; v3 = fmaxf(v3, 0.01f * v3);
        uint2 pk; pk.x = pk_bf16(v0, v1); pk.y = pk_bf16(v2, v3);
        *(uint2*)&h[wc * 64 + nf * 16 + l15][wr * 64 + mf * 16 + l4 * 4] = pk;
      }
    __syncthreads();
    // ---- layer 2: [256 ch] x [128 px], K=256
    f32x4 a2[4][4];
#pragma unroll
    for (int mf = 0; mf < 4; ++mf) {
      const ushort4 bq = *(const ushort4*)(F + BIAS2 + wr * 64 + mf * 16 + l4 * 4);
      const f32x4 bi = {bf2f(bq.x), bf2f(bq.y), bf2f(bq.z), bf2f(bq.w)};
#pragma unroll
      for (int nf = 0; nf < 4; ++nf) a2[mf][nf] = bi;
    }
#pragma unroll 2
    for (int ks = 0; ks < 8; ++ks) {
      bf16x8 W2[4];
#pragma unroll
      for (int mf = 0; mf < 4; ++mf)
        W2[mf] = *(const bf16x8*)(F + BEG2 + (size_t)(wr * 64 + mf * 16 + l15) * 256 + ks * 32 + l4 * 8);
#pragma unroll
      for (int nf = 0; nf < 4; ++nf) {
        const bf16x8 X2 = *(const bf16x8*)&h[wc * 64 + nf * 16 + l15][ks * 32 + l4 * 8];
#pragma unroll
        for (int mf = 0; mf < 4; ++mf)
          a2[mf][nf] = __builtin_amdgcn_mfma_f32_16x16x32_bf16(W2[mf], X2, a2[mf][nf], 0, 0, 0);
      }
    }
    __syncthreads();
#pragma unroll
    for (int mf = 0; mf < 4; ++mf)
#pragma unroll
      for (int nf = 0; nf < 4; ++nf) {
        float v0 = a2[mf][nf][0]; v0 = fmaxf(v0, 0.01f * v0);
        float v1 = a2[mf][nf][1]; v1 = fmaxf(v1, 0.01f * v1);
        float v2 = a2[mf][nf][2]; v2 = fmaxf(v2, 0.01f * v2);
        float v3 = a2[mf][nf][3]; v3 = fmaxf(v3, 0.01f * v3);
        uint2 pk; pk.x = pk_bf16(v0, v1); pk.y = pk_bf16(v2, v3);
        *(uint2*)&h[wc * 64 + nf * 16 + l15][wr * 64 + mf * 16 + l4 * 4] = pk;
      }
    __syncthreads();
    // ---- layer 3: [64 ch] x [128 px], K=256 -> direct out stores
    f32x4 a3[4];
    {
      const ushort4 bq = *(const ushort4*)(F + BIAS3 + wr * 16 + l4 * 4);
      const f32x4 bi = {bf2f(bq.x), bf2f(bq.y), bf2f(bq.z), bf2f(bq.w)};
#pragma unroll
      for (int nf = 0; nf < 4; ++nf) a3[nf] = bi;
    }
#pragma unroll 2
    for (int ks = 0; ks < 8; ++ks) {
      const bf16x8 W3 = *(const bf16x8*)(F + BEG3 + (size_t)(wr * 16 + l15) * 256 + ks * 32 + l4 * 8);
#pragma unroll
      for (int nf = 0; nf < 4; ++nf) {
        const bf16x8 X3 = *(const bf16x8*)&h[wc * 64 + nf * 16 + l15][ks * 32 + l4 * 8];
        a3[nf] = __builtin_amdgcn_mfma_f32_16x16x32_bf16(W3, X3, a3[nf], 0, 0, 0);
      }
    }
#pragma unroll
    for (int nf = 0; nf < 4; ++nf) {
      const int p = p0 + wc * 64 + nf * 16 + l15;
      const int s = p >> 6, ph = (p >> 3) & 7, pw = p & 7;
      const size_t rowcol = (size_t)s * 4096 + (ah * 8 + ph) * 64 + aw * 8 + pw;
#pragma unroll
      for (int oc = 0; oc < 4; ++oc) {
        const int o = wr * 16 + l4 * 4 + oc;
        out[(size_t)(bb * 64 + o) * 32768 + rowcol] = a3[nf][oc];
      }
    }
    __syncthreads();
  }
}

extern "C" void kernel_launch(void* const* d_in, const int* in_sizes, int n_in,
                              void* d_out, int out_size, void* d_ws, size_t ws_size,
                              hipStream_t stream) {
  const float* mlp      = (const float*)d_in[0];
  const float* coord_em = (const float*)d_in[1];
  const float* coord_dt = (const float*)d_in[2];
  const float* w_cd     = (const float*)d_in[3];
  const float* b_cd     = (const float*)d_in[4];
  const float* w_feat   = (const float*)d_in[5];
  const float* b_feat   = (const float*)d_in[6];
  float* out = (float*)d_out;
  unsigned short* featb = (unsigned short*)d_ws;                         // 46,432,256
  unsigned short* xinb  = (unsigned short*)((char*)d_ws + 46432256ull);  // 8,388,608
  unsigned short* mlpT  = (unsigned short*)((char*)d_ws + 54820864ull);  // 131,072

  mlp_tr<<<16, 256, 0, stream>>>(mlp, mlpT);
  fused_prep<<<NFEATBLK + 1024, 256, 0, stream>>>(
      w_feat, b_feat, mlpT, featb, coord_em, coord_dt, w_cd, b_cd, xinb);
  tile_mlp<<<512, 512, 0, stream>>>(featb, xinb, out);
}

// Round 29
// 102.685 us; speedup vs baseline: 1.0490x; 1.0029x over previous
//
#include <hip/hip_runtime.h>

typedef __attribute__((ext_vector_type(8))) short bf16x8;
typedef __attribute__((ext_vector_type(8))) unsigned short ushort8;
typedef __attribute__((ext_vector_type(4))) float f32x4;

#define IN_CH   32
#define OUT_CH  64
#define FEAT_CH 256
#define PTOT    32768
#define CTOT    90688
#define BEG1    0
#define BIAS1   8192
#define BEG2    8448
#define BIAS2   73984
#define BEG3    74240
#define BIAS3   90624
#define NFEATBLK 1417

__device__ __forceinline__ unsigned short f2bf(float f) {
  __bf16 h = (__bf16)f;
  return __builtin_bit_cast(unsigned short, h);
}
__device__ __forceinline__ float bf2f(unsigned short h) {
  union { unsigned u; float f; } v; v.u = ((unsigned)h) << 16;
  return v.f;
}
__device__ __forceinline__ unsigned pk_bf16(float lo, float hi) {  // D[15:0]=bf16(lo)
  unsigned r;
  asm("v_cvt_pk_bf16_f32 %0, %1, %2" : "=v"(r) : "v"(lo), "v"(hi));
  return r;
}
__device__ __forceinline__ void gload16(const void* g, void* l) {
  __builtin_amdgcn_global_load_lds(
      (const __attribute__((address_space(1))) unsigned int*)g,
      (__attribute__((address_space(3))) unsigned int*)l, 16, 0, 0);
}

// ============ mlp transpose: mlpT[n][k] = bf16(mlp[b][k][a]), n = b*64+a
__global__ __launch_bounds__(256) void mlp_tr(
    const float* __restrict__ mlp, unsigned short* __restrict__ mlpT) {
  __shared__ float t[64][65];
  const int b = blockIdx.x >> 2, k0 = (blockIdx.x & 3) << 6;
  const int tid = threadIdx.x;
  const int a = tid & 63, kq = tid >> 6;
#pragma unroll
  for (int j = 0; j < 16; ++j) {
    const int k = kq * 16 + j;
    t[k][a] = mlp[(size_t)b * 16384 + (size_t)(k0 + k) * 64 + a];
  }
  __syncthreads();
  const int a2 = tid >> 2, c4 = tid & 3;
  ushort8 o0, o1;
#pragma unroll
  for (int j = 0; j < 8; ++j)  o0[j] = f2bf(t[c4 * 16 + j][a2]);
#pragma unroll
  for (int j = 0; j < 8; ++j)  o1[j] = f2bf(t[c4 * 16 + 8 + j][a2]);
  unsigned short* dst = mlpT + (size_t)(b * 64 + a2) * 256 + k0 + c4 * 16;
  *(ushort8*)dst = o0;
  *(ushort8*)(dst + 8) = o1;
}

// ============ FUSED (R25-passing build): blocks 0..1416 feat, 1417..2440 coord.
// Feat: A in registers (lane's own row, 32 VGPR), Bsh single 16KB buffer
// staged via source-swizzled global_load_lds, 8 np phases.
__global__ __launch_bounds__(256) void fused_prep(
    const float* __restrict__ w_feat, const float* __restrict__ b_feat,
    const unsigned short* __restrict__ mlpT, unsigned short* __restrict__ featb,
    const float* __restrict__ coord_em, const float* __restrict__ coord_dt,
    const float* __restrict__ w_cd, const float* __restrict__ b_cd,
    unsigned short* __restrict__ xinb) {
  __shared__ unsigned short Bsh[32][256];     // 16KB (swizzled, no pad)
  const int tid = threadIdx.x;
  const int lane = tid & 63;

  if (blockIdx.x < NFEATBLK) {
    // ---------------- feat GEMM ----------------
    const int w = tid >> 6;
    const int l15 = lane & 15, l4 = lane >> 4;
    const int m0 = blockIdx.x * 64;           // 1417*64 == CTOT
    const int arow = m0 + w * 16 + l15;

    // A fragments: this lane's own row, full K, cvt once, live all phases.
    const float* __restrict__ ar = w_feat + (size_t)arow * 256 + l4 * 8;
    bf16x8 A[8];
#pragma unroll
    for (int ks = 0; ks < 8; ++ks) {
      const float4 p0 = *(const float4*)(ar + ks * 32);
      const float4 p1 = *(const float4*)(ar + ks * 32 + 4);
      unsigned t[4] = {pk_bf16(p0.x, p0.y), pk_bf16(p0.z, p0.w),
                       pk_bf16(p1.x, p1.y), pk_bf16(p1.z, p1.w)};
      A[ks] = __builtin_bit_cast(bf16x8, *(ulonglong2*)t);
    }

    const int c = m0 + w * 16 + l4 * 4;
    const float4 bia = *(const float4*)&b_feat[c];
    const int drow = lane >> 5;               // 0..1
    const int dchk = lane & 31;               // 0..31

    for (int np = 0; np < 8; ++np) {
      const int n0 = np * 32;
#pragma unroll
      for (int j = 0; j < 4; ++j) {
        const int row = w * 8 + j * 2 + drow;
        gload16(mlpT + (size_t)(n0 + row) * 256 + ((dchk ^ (row & 7)) << 3),
                &Bsh[w * 8 + j * 2][0]);
      }
      __syncthreads();   // vmcnt drain = staging complete

      f32x4 acc[2];
#pragma unroll
      for (int nf = 0; nf < 2; ++nf) acc[nf] = f32x4{0.f, 0.f, 0.f, 0.f};

#pragma unroll
      for (int ks = 0; ks < 8; ++ks) {
        bf16x8 Bv[2];
#pragma unroll
        for (int nf = 0; nf < 2; ++nf) {
          const int brow = nf * 16 + l15;
          const int cc = (ks * 4 + l4) ^ (brow & 7);
          Bv[nf] = *(const bf16x8*)&Bsh[brow][cc * 8];
        }
#pragma unroll
        for (int nf = 0; nf < 2; ++nf)
          acc[nf] = __builtin_amdgcn_mfma_f32_16x16x32_bf16(A[ks], Bv[nf], acc[nf], 0, 0, 0);
      }

#pragma unroll
      for (int nf = 0; nf < 2; ++nf) {
        const int n = n0 + nf * 16 + l15;
        ushort4 o;
        o.x = f2bf(acc[nf][0] + bia.x);
        o.y = f2bf(acc[nf][1] + bia.y);
        o.z = f2bf(acc[nf][2] + bia.z);
        o.w = f2bf(acc[nf][3] + bia.w);
        *(ushort4*)(featb + (size_t)n * CTOT + c) = o;
      }
      __syncthreads();   // Bsh reads done before next pass overwrites
    }
  } else {
    // ---------------- coord_prep (verbatim body) ----------------
    const int ohalf = __builtin_amdgcn_readfirstlane((tid >> 6) & 1);
    const int pgrp = (blockIdx.x - NFEATBLK) * 2 + (tid >> 7);
    const int p_lin = pgrp * 64 + lane;
    const int b = p_lin >> 15, p = p_lin & 32767;

    const float* __restrict__ cdr = coord_dt + (size_t)p_lin * 64;
    float4 x[16];
#pragma unroll
    for (int j = 0; j < 16; ++j) x[j] = *(const float4*)(cdr + j * 4);
    __builtin_amdgcn_sched_barrier(0);

    float acc[16];
#pragma unroll
    for (int oo = 0; oo < 16; ++oo) acc[oo] = 0.f;
    const float* __restrict__ wr = w_cd + (size_t)(ohalf * 16) * 64;
#pragma unroll
    for (int oo = 0; oo < 16; ++oo) {
#pragma unroll
      for (int j = 0; j < 16; ++j) {
        acc[oo] = fmaf(wr[oo * 64 + j * 4 + 0], x[j].x, acc[oo]);
        acc[oo] = fmaf(wr[oo * 64 + j * 4 + 1], x[j].y, acc[oo]);
        acc[oo] = fmaf(wr[oo * 64 + j * 4 + 2], x[j].z, acc[oo]);
        acc[oo] = fmaf(wr[oo * 64 + j * 4 + 3], x[j].w, acc[oo]);
      }
    }

    float e[16];
#pragma unroll
    for (int oo = 0; oo < 16; ++oo) {
      const int o = ohalf * 16 + oo;
      e[oo] = acc[oo] + b_cd[o] + coord_em[((size_t)(b * IN_CH + o)) * PTOT + p];
    }
    const int s = p >> 12, rem = p & 4095;
    const int oh = rem >> 6, ow = rem & 63;
    const int a = ((oh >> 3) << 3) | (ow >> 3);
    const int pp = (s << 6) | ((oh & 7) << 3) | (ow & 7);
    unsigned short* __restrict__ dst =
        xinb + ((size_t)((b << 6) + a) * 512 + pp) * IN_CH + ohalf * 16;
    unsigned u[8];
#pragma unroll
    for (int q = 0; q < 8; ++q) u[q] = pk_bf16(e[2 * q], e[2 * q + 1]);
    *(ulonglong2*)dst = *(ulonglong2*)&u[0];
    *(ulonglong2*)(dst + 8) = *(ulonglong2*)&u[4];
  }
}

// ============ Stage C: swapped-operand MFMA MLP (R20-passing body, unchanged).
__global__ __launch_bounds__(512, 4) void tile_mlp(
    const unsigned short* __restrict__ featb, const unsigned short* __restrict__ xinb,
    float* __restrict__ out) {
  __shared__ unsigned short h[128][264];   // 67.6KB, row stride 528B (2-way banks: free)
  const int blk = blockIdx.x;
  const int tile = (blk & 7) * 32 + (blk >> 4);   // both halves of a tile -> same XCD
  const int half = (blk >> 3) & 1;
  const int tid = threadIdx.x;
  const int lane = tid & 63;
  const int wv = tid >> 6;
  const int wr = wv & 3, wc = wv >> 2;
  const int l15 = lane & 15, l4 = lane >> 4;
  const unsigned short* __restrict__ F = featb + (size_t)tile * CTOT;
  const int bb = tile >> 6, aa = tile & 63;
  const int ah = aa >> 3, aw = aa & 7;

  for (int ch2 = 0; ch2 < 2; ++ch2) {
    const int p0 = half * 256 + ch2 * 128;
    // ---- layer 1: [256 ch] x [128 px], K=32
    f32x4 a1[4][4];
#pragma unroll
    for (int mf = 0; mf < 4; ++mf) {
      const ushort4 bq = *(const ushort4*)(F + BIAS1 + wr * 64 + mf * 16 + l4 * 4);
      const f32x4 bi = {bf2f(bq.x), bf2f(bq.y), bf2f(bq.z), bf2f(bq.w)};
#pragma unroll
      for (int nf = 0; nf < 4; ++nf) a1[mf][nf] = bi;
    }
    {
      bf16x8 W1[4];
#pragma unroll
      for (int mf = 0; mf < 4; ++mf)
        W1[mf] = *(const bf16x8*)(F + BEG1 + (size_t)(wr * 64 + mf * 16 + l15) * 32 + l4 * 8);
#pragma unroll
      for (int nf = 0; nf < 4; ++nf) {
        const bf16x8 X1 = *(const bf16x8*)(xinb +
            ((size_t)tile * 512 + p0 + wc * 64 + nf * 16 + l15) * IN_CH + l4 * 8);
#pragma unroll
        for (int mf = 0; mf < 4; ++mf)
          a1[mf][nf] = __builtin_amdgcn_mfma_f32_16x16x32_bf16(W1[mf], X1, a1[mf][nf], 0, 0, 0);
      }
    }
#pragma unroll
    for (int mf = 0; mf < 4; ++mf)
#pragma unroll
      for (int nf = 0; nf < 4; ++nf) {
        float v0 = a1[mf][nf][0]; v0 = fmaxf(v0, 0.01f * v0);
        float v1 = a1[mf][nf][1]; v1 = fmaxf(v1, 0.01f * v1);
        float v2 = a1[mf][nf][2]; v2 = fmaxf(v2, 0.01f * v2);
        float v3 = a1[mf][nf][3]; v3 = fmaxf(v3, 0.01f * v3);
        uint2 pk; pk.x = pk_bf16(v0, v1); pk.y = pk_bf16(v2, v3);
        *(uint2*)&h[wc * 64 + nf * 16 + l15][wr * 64 + mf * 16 + l4 * 4] = pk;
      }
    __syncthreads();
    // ---- layer 2: [256 ch] x [128 px], K=256
    f32x4 a2[4][4];
#pragma unroll
    for (int mf = 0; mf < 4; ++mf) {
      const ushort4 bq = *(const ushort4*)(F + BIAS2 + wr * 64 + mf * 16 + l4 * 4);
      const f32x4 bi = {bf2f(bq.x), bf2f(bq.y), bf2f(bq.z), bf2f(bq.w)};
#pragma unroll
      for (int nf = 0; nf < 4; ++nf) a2[mf][nf] = bi;
    }
#pragma unroll 2
    for (int ks = 0; ks < 8; ++ks) {
      bf16x8 W2[4];
#pragma unroll
      for (int mf = 0; mf < 4; ++mf)
        W2[mf] = *(const bf16x8*)(F + BEG2 + (size_t)(wr * 64 + mf * 16 + l15) * 256 + ks * 32 + l4 * 8);
#pragma unroll
      for (int nf = 0; nf < 4; ++nf) {
        const bf16x8 X2 = *(const bf16x8*)&h[wc * 64 + nf * 16 + l15][ks * 32 + l4 * 8];
#pragma unroll
        for (int mf = 0; mf < 4; ++mf)
          a2[mf][nf] = __builtin_amdgcn_mfma_f32_16x16x32_bf16(W2[mf], X2, a2[mf][nf], 0, 0, 0);
      }
    }
    __syncthreads();
#pragma unroll
    for (int mf = 0; mf < 4; ++mf)
#pragma unroll
      for (int nf = 0; nf < 4; ++nf) {
        float v0 = a2[mf][nf][0]; v0 = fmaxf(v0, 0.01f * v0);
        float v1 = a2[mf][nf][1]; v1 = fmaxf(v1, 0.01f * v1);
        float v2 = a2[mf][nf][2]; v2 = fmaxf(v2, 0.01f * v2);
        float v3 = a2[mf][nf][3]; v3 = fmaxf(v3, 0.01f * v3);
        uint2 pk; pk.x = pk_bf16(v0, v1); pk.y = pk_bf16(v2, v3);
        *(uint2*)&h[wc * 64 + nf * 16 + l15][wr * 64 + mf * 16 + l4 * 4] = pk;
      }
    __syncthreads();
    // ---- layer 3: [64 ch] x [128 px], K=256 -> direct out stores
    f32x4 a3[4];
    {
      const ushort4 bq = *(const ushort4*)(F + BIAS3 + wr * 16 + l4 * 4);
      const f32x4 bi = {bf2f(bq.x), bf2f(bq.y), bf2f(bq.z), bf2f(bq.w)};
#pragma unroll
      for (int nf = 0; nf < 4; ++nf) a3[nf] = bi;
    }
#pragma unroll 2
    for (int ks = 0; ks < 8; ++ks) {
      const bf16x8 W3 = *(const bf16x8*)(F + BEG3 + (size_t)(wr * 16 + l15) * 256 + ks * 32 + l4 * 8);
#pragma unroll
      for (int nf = 0; nf < 4; ++nf) {
        const bf16x8 X3 = *(const bf16x8*)&h[wc * 64 + nf * 16 + l15][ks * 32 + l4 * 8];
        a3[nf] = __builtin_amdgcn_mfma_f32_16x16x32_bf16(W3, X3, a3[nf], 0, 0, 0);
      }
    }
#pragma unroll
    for (int nf = 0; nf < 4; ++nf) {
      const int p = p0 + wc * 64 + nf * 16 + l15;
      const int s = p >> 6, ph = (p >> 3) & 7, pw = p & 7;
      const size_t rowcol = (size_t)s * 4096 + (ah * 8 + ph) * 64 + aw * 8 + pw;
#pragma unroll
      for (int oc = 0; oc < 4; ++oc) {
        const int o = wr * 16 + l4 * 4 + oc;
        out[(size_t)(bb * 64 + o) * 32768 + rowcol] = a3[nf][oc];
      }
    }
    __syncthreads();
  }
}

extern "C" void kernel_launch(void* const* d_in, const int* in_sizes, int n_in,
                              void* d_out, int out_size, void* d_ws, size_t ws_size,
                              hipStream_t stream) {
  const float* mlp      = (const float*)d_in[0];
  const float* coord_em = (const float*)d_in[1];
  const float* coord_dt = (const float*)d_in[2];
  const float* w_cd     = (const float*)d_in[3];
  const float* b_cd     = (const float*)d_in[4];
  const float* w_feat   = (const float*)d_in[5];
  const float* b_feat   = (const float*)d_in[6];
  float* out = (float*)d_out;
  unsigned short* featb = (unsigned short*)d_ws;                         // 46,432,256
  unsigned short* xinb  = (unsigned short*)((char*)d_ws + 46432256ull);  // 8,388,608
  unsigned short* mlpT  = (unsigned short*)((char*)d_ws + 54820864ull);  // 131,072

  mlp_tr<<<16, 256, 0, stream>>>(mlp, mlpT);
  fused_prep<<<NFEATBLK + 1024, 256, 0, stream>>>(
      w_feat, b_feat, mlpT, featb, coord_em, coord_dt, w_cd, b_cd, xinb);
  tile_mlp<<<512, 512, 0, stream>>>(featb, xinb, out);
}